// Round 6
// baseline (380.793 us; speedup 1.0000x reference)
//
#include <hip/hip_runtime.h>
#include <math.h>

#define NQ    2048
#define DIM   128
#define PD    256
#define NPOOL 262144
#define TOPK  32
#define CAP   512
#define ZTHR  3.2f

#define QBA   64                 // q rows per block (kernel A)
#define CKA   64                 // keys per chunk (wave owns 16)
#define SLABS 64
#define SLABK (NPOOL / SLABS)    // 4096 keys per slab
#define NCH   (SLABK / CKA)      // 64 chunks per block
#define LBUF  1024               // per-block LDS candidate buffer (mean ~190)

typedef __attribute__((ext_vector_type(8))) __bf16 bf16x8;
typedef __attribute__((ext_vector_type(4))) float  f32x4;
typedef __attribute__((ext_vector_type(4))) unsigned short us4;

__device__ __forceinline__ unsigned short f2bf(float v) {
    return (unsigned short)(__float_as_uint(v) >> 16);   // truncation: fine for prefilter
}

// ---------------------------------------------------------------------------
// P1: convert keys f32 -> bf16 (truncated)
// ---------------------------------------------------------------------------
__global__ __launch_bounds__(256)
void convert_keys(const float4* __restrict__ k4, us4* __restrict__ kb)
{
    const size_t total = (size_t)NPOOL * DIM / 4;   // 8,388,608 float4
    size_t stride = (size_t)gridDim.x * blockDim.x;
    for (size_t i = blockIdx.x * (size_t)blockDim.x + threadIdx.x; i < total; i += stride) {
        float4 v = k4[i];
        us4 o;
        o.x = f2bf(v.x); o.y = f2bf(v.y); o.z = f2bf(v.z); o.w = f2bf(v.w);
        kb[i] = o;
    }
}

// ---------------------------------------------------------------------------
// P2: per-row ||q||, tau, q->bf16, zero cnt; tail blocks transpose w_out.
// grid = NQ + PD, block = 128
// ---------------------------------------------------------------------------
__global__ __launch_bounds__(128)
void prep_q(const float* __restrict__ q, unsigned short* __restrict__ qb16,
            float* __restrict__ tau, int* __restrict__ cnt,
            const float* __restrict__ w, float* __restrict__ wt)
{
    const int bid = blockIdx.x, t = threadIdx.x;
    if (bid >= NQ) {                       // transpose w_out [o][d] -> wt [d][o]
        int o = bid - NQ;
        wt[t * PD + o]         = w[o * PD + t];
        wt[(t + 128) * PD + o] = w[o * PD + t + 128];
        return;
    }
    const int row = bid;
    float v = q[(size_t)row * DIM + t];
    qb16[(size_t)row * DIM + t] = f2bf(v);
    float s = v * v;
    #pragma unroll
    for (int off = 32; off; off >>= 1) s += __shfl_xor(s, off);
    __shared__ float part[2];
    if ((t & 63) == 0) part[t >> 6] = s;
    __syncthreads();
    if (t == 0) {
        float nn = part[0] + part[1];
        tau[row] = ZTHR * 0.02f * sqrtf(nn);
        cnt[row] = 0;
    }
}

// ---------------------------------------------------------------------------
// A: bf16 MFMA scores, keys loaded directly into B-fragment registers.
//    3-buffer / prefetch-distance-2 register pipeline, no loop barriers.
//    Per-lane max/branch filter -> LDS candidate buffer, bulk flush at end.
// grid = 32 qblocks * 64 slabs = 2048 blocks, 256 threads (4 waves)
// ---------------------------------------------------------------------------
__global__ __launch_bounds__(256, 3)
void score_filter_kernel(const unsigned short* __restrict__ qb16, // [NQ][DIM]
                         const unsigned short* __restrict__ kb16, // [NPOOL][DIM]
                         const float* __restrict__ tau,
                         int* __restrict__ cnt,
                         int* __restrict__ cand_i)                // [NQ][CAP]
{
    __shared__ float taus[QBA];
    __shared__ unsigned int lbuf[LBUF];
    __shared__ int lcnt;

    // XCD-chunked swizzle (2048 blocks, 8 XCDs): slab varies slowly per XCD
    const int bid  = blockIdx.x;
    const int swz  = (bid & 7) * 256 + (bid >> 3);
    const int slab = swz >> 5;       // 0..63
    const int qblk = swz & 31;       // 0..31
    const int qbase = qblk * QBA;
    const int kslab = slab * SLABK;

    const int t    = threadIdx.x;
    const int lane = t & 63;
    const int wave = t >> 6;

    if (t == 0) lcnt = 0;
    if (t < QBA) taus[t] = tau[qbase + t];

    // Q fragments: A[row=lane&15][k=(lane>>4)*8+j], rowgroup g, kchunk kc
    bf16x8 qf[4][4];
    #pragma unroll
    for (int g = 0; g < 4; ++g)
        #pragma unroll
        for (int kc = 0; kc < 4; ++kc)
            qf[g][kc] = *(const bf16x8*)&qb16[(size_t)(qbase + g * 16 + (lane & 15)) * DIM
                                             + kc * 32 + (lane >> 4) * 8];

    __syncthreads();   // taus visible

    // per-lane tau registers + per-lane min for the fast-path branch
    float tr[4][4];
    float tmin = 1e30f;
    #pragma unroll
    for (int g = 0; g < 4; ++g)
        #pragma unroll
        for (int r = 0; r < 4; ++r) {
            tr[g][r] = taus[g * 16 + (lane >> 4) * 4 + r];
            tmin = fminf(tmin, tr[g][r]);
        }

    const int key = wave * 16 + (lane & 15);
    // per-lane B-fragment source: row 'key', byte (lane>>4)*16 within each 64B kc block
    const char* kpb = (const char*)kb16
                    + ((size_t)(kslab + key) * DIM + (lane >> 4) * 8) * 2;

#define KLOAD(DST, CH) do {                                             \
        const char* p_ = kpb + (size_t)(CH) * (CKA * DIM * 2);          \
        DST[0] = *(const bf16x8*)(p_);                                  \
        DST[1] = *(const bf16x8*)(p_ + 64);                             \
        DST[2] = *(const bf16x8*)(p_ + 128);                            \
        DST[3] = *(const bf16x8*)(p_ + 192); } while (0)

#define COMPUTE(KREG, CH) do {                                                  \
        f32x4 acc[4] = {{0,0,0,0},{0,0,0,0},{0,0,0,0},{0,0,0,0}};               \
        _Pragma("unroll")                                                       \
        for (int kc = 0; kc < 4; ++kc) {                                        \
            _Pragma("unroll")                                                   \
            for (int g = 0; g < 4; ++g)                                         \
                acc[g] = __builtin_amdgcn_mfma_f32_16x16x32_bf16(               \
                             qf[g][kc], KREG[kc], acc[g], 0, 0, 0);             \
        }                                                                       \
        float mx0 = fmaxf(fmaxf(acc[0][0], acc[0][1]), fmaxf(acc[0][2], acc[0][3])); \
        float mx1 = fmaxf(fmaxf(acc[1][0], acc[1][1]), fmaxf(acc[1][2], acc[1][3])); \
        float mx2 = fmaxf(fmaxf(acc[2][0], acc[2][1]), fmaxf(acc[2][2], acc[2][3])); \
        float mx3 = fmaxf(fmaxf(acc[3][0], acc[3][1]), fmaxf(acc[3][2], acc[3][3])); \
        float mx  = fmaxf(fmaxf(mx0, mx1), fmaxf(mx2, mx3));                    \
        if (mx > tmin) {                                                        \
            const unsigned keyl = (unsigned)((CH) * CKA + key);                 \
            _Pragma("unroll")                                                   \
            for (int g = 0; g < 4; ++g) {                                       \
                _Pragma("unroll")                                               \
                for (int r = 0; r < 4; ++r) {                                   \
                    if (acc[g][r] > tr[g][r]) {                                 \
                        int idx = atomicAdd(&lcnt, 1);                          \
                        if (idx < LBUF)                                         \
                            lbuf[idx] = ((unsigned)(g * 16 + (lane >> 4) * 4 + r) << 12) | keyl; \
                    }                                                           \
                }                                                               \
            }                                                                   \
        } } while (0)

    // 3-buffer register pipeline, prefetch distance 2 (~2 chunks of compute
    // in flight per load ≈ 200+ cyc ≥ L2-hit latency).  NCH = 64 = 2 + 3*20 + 2.
    bf16x8 k0[4], k1[4], k2[4];
    KLOAD(k0, 0);
    KLOAD(k1, 1);
    int ch = 0;
    #pragma unroll 1
    for (int it = 0; it < 21; ++it, ch += 3) {
        KLOAD(k2, ch + 2);
        COMPUTE(k0, ch);
        if (ch + 3 < NCH) KLOAD(k0, ch + 3);
        COMPUTE(k1, ch + 1);
        if (ch + 4 < NCH) KLOAD(k1, ch + 4);
        COMPUTE(k2, ch + 2);
    }
    COMPUTE(k0, 63);   // loaded at it=20 (ch+3 == 63)
#undef KLOAD
#undef COMPUTE

    __syncthreads();   // lbuf/lcnt visible
    const int n = min(lcnt, LBUF);
    for (int i = t; i < n; i += 256) {
        unsigned e = lbuf[i];
        int row  = qbase + (int)(e >> 12);
        int keyg = kslab + (int)(e & 4095u);
        int slot = atomicAdd(&cnt[row], 1);
        if (slot < CAP) cand_i[(size_t)row * CAP + slot] = keyg;
    }
}

// ---------------------------------------------------------------------------
// B: f32 rescore of candidates -> exact top-32 -> softmax -> gather -> matmul
// grid = NQ, 256 threads
// ---------------------------------------------------------------------------
__global__ __launch_bounds__(256)
void rescore_agg_kernel(const float* __restrict__ q,
                        const float* __restrict__ keys,
                        const float* __restrict__ pool,
                        const float* __restrict__ wt,
                        const int* __restrict__ cnt,
                        const int* __restrict__ cand_i,
                        float* __restrict__ out)
{
    __shared__ float qrow[DIM];
    __shared__ float ls[CAP];
    __shared__ int   li[CAP];
    __shared__ float red_s[4];
    __shared__ int   red_p[4];
    __shared__ float sel_s[TOPK];
    __shared__ int   sel_i[TOPK];
    __shared__ float wts[TOPK];
    __shared__ float agg[PD];

    const int t   = threadIdx.x;
    const int row = blockIdx.x;
    const int n   = min(cnt[row], CAP);

    if (t < DIM) qrow[t] = q[(size_t)row * DIM + t];
    for (int i = t; i < CAP; i += 256) { ls[i] = -1e30f; li[i] = 0; }
    __syncthreads();

    // rescore: 16 groups of 16 lanes; group handles candidates strided by 16
    const int grp = t >> 4, gl = t & 15;
    for (int c = grp; c < n; c += 16) {
        int ki = cand_i[(size_t)row * CAP + c];
        const float4* kr4 = (const float4*)(keys + (size_t)ki * DIM + gl * 8);
        float4 k0 = kr4[0], k1 = kr4[1];
        const float* qq = &qrow[gl * 8];
        float s = qq[0]*k0.x + qq[1]*k0.y + qq[2]*k0.z + qq[3]*k0.w
                + qq[4]*k1.x + qq[5]*k1.y + qq[6]*k1.z + qq[7]*k1.w;
        s += __shfl_xor(s, 1); s += __shfl_xor(s, 2);
        s += __shfl_xor(s, 4); s += __shfl_xor(s, 8);
        if (gl == 0) { ls[c] = s; li[c] = ki; }
    }
    __syncthreads();

    // exact top-32 (iterative argmax over CAP slots; tie-break lower key idx)
    for (int k = 0; k < TOPK; ++k) {
        float bs = ls[t]; int bp = t;
        {
            float s2 = ls[t + 256];
            if (s2 > bs || (s2 == bs && li[t + 256] < li[bp])) { bs = s2; bp = t + 256; }
        }
        #pragma unroll
        for (int off = 1; off < 64; off <<= 1) {
            float os = __shfl_xor(bs, off);
            int   op = __shfl_xor(bp, off);
            if (os > bs || (os == bs && li[op] < li[bp])) { bs = os; bp = op; }
        }
        if ((t & 63) == 0) { red_s[t >> 6] = bs; red_p[t >> 6] = bp; }
        __syncthreads();
        if (t == 0) {
            float best = red_s[0]; int p = red_p[0];
            #pragma unroll
            for (int w = 1; w < 4; ++w) {
                float s2 = red_s[w]; int p2 = red_p[w];
                if (s2 > best || (s2 == best && li[p2] < li[p])) { best = s2; p = p2; }
            }
            sel_s[k] = best; sel_i[k] = li[p];
            ls[p] = -1e30f;
        }
        __syncthreads();
    }

    // softmax over 32 (sel_s[0] is max; empty slots give exp(-huge)=0)
    if (t < 64) {
        float e = (t < TOPK) ? expf(sel_s[t] - sel_s[0]) : 0.f;
        float v = e;
        #pragma unroll
        for (int off = 1; off < 64; off <<= 1) v += __shfl_xor(v, off);
        if (t < TOPK) wts[t] = e / v;
    }
    __syncthreads();

    // weighted gather: thread t owns pool dim t
    float a = 0.f;
    #pragma unroll
    for (int k = 0; k < TOPK; ++k)
        a += wts[k] * pool[(size_t)sel_i[k] * PD + t];
    agg[t] = a;
    __syncthreads();

    // out[row][o] = sum_d agg[d] * wt[d][o]
    float o = 0.f;
    #pragma unroll 8
    for (int d = 0; d < PD; ++d)
        o += agg[d] * wt[d * PD + t];
    out[(size_t)row * PD + t] = o;
}

extern "C" void kernel_launch(void* const* d_in, const int* in_sizes, int n_in,
                              void* d_out, int out_size, void* d_ws, size_t ws_size,
                              hipStream_t stream)
{
    const float* q    = (const float*)d_in[0];   // [2,1024,128]
    const float* pool = (const float*)d_in[1];   // [262144,256]
    const float* keys = (const float*)d_in[2];   // [262144,128]
    const float* w    = (const float*)d_in[3];   // [256,256]
    float* out = (float*)d_out;

    char* ws = (char*)d_ws;
    unsigned short* kb16  = (unsigned short*)(ws);                    // 67,108,864 B
    unsigned short* qb16  = (unsigned short*)(ws + 67108864);         //    524,288 B
    float*          tau   = (float*)(ws + 67633152);                  //      8,192 B
    int*            cnt   = (int*)(ws + 67641344);                    //      8,192 B
    int*            candi = (int*)(ws + 67649536);                    //  4,194,304 B
    float*          wt    = (float*)(ws + 71843840);                  //    262,144 B

    hipLaunchKernelGGL(convert_keys, dim3(2048), dim3(256), 0, stream,
                       (const float4*)keys, (us4*)kb16);
    hipLaunchKernelGGL(prep_q, dim3(NQ + PD), dim3(128), 0, stream,
                       q, qb16, tau, cnt, w, wt);
    hipLaunchKernelGGL(score_filter_kernel, dim3(2048), dim3(256), 0, stream,
                       qb16, kb16, tau, cnt, candi);
    hipLaunchKernelGGL(rescore_agg_kernel, dim3(NQ), dim3(256), 0, stream,
                       q, keys, pool, wt, cnt, candi, out);
}

// Round 7
// 341.424 us; speedup vs baseline: 1.1153x; 1.1153x over previous
//
#include <hip/hip_runtime.h>
#include <math.h>

#define NQ    2048
#define DIM   128
#define PD    256
#define NPOOL 262144
#define TOPK  32
#define CAP   512
#define ZTHR  3.2f

#define QBA   64                 // q rows per block (kernel A)
#define CKA   64                 // keys per chunk (wave owns 16)
#define SLABS 64
#define SLABK (NPOOL / SLABS)    // 4096 keys per slab
#define NCH   (SLABK / CKA)      // 64 chunks per block
#define LBUF  1024               // per-block LDS candidate buffer (mean ~190)

typedef __attribute__((ext_vector_type(8))) __bf16 bf16x8;
typedef __attribute__((ext_vector_type(4))) float  f32x4;
typedef __attribute__((ext_vector_type(4))) unsigned short us4;

__device__ __forceinline__ void gload_lds16(const void* gsrc, void* ldst) {
    __builtin_amdgcn_global_load_lds(
        (const __attribute__((address_space(1))) void*)gsrc,
        (__attribute__((address_space(3))) void*)ldst, 16, 0, 0);
}

__device__ __forceinline__ unsigned short f2bf(float v) {
    return (unsigned short)(__float_as_uint(v) >> 16);   // truncation: fine for prefilter
}

// ---------------------------------------------------------------------------
// P1: convert keys f32 -> bf16 (truncated)
// ---------------------------------------------------------------------------
__global__ __launch_bounds__(256)
void convert_keys(const float4* __restrict__ k4, us4* __restrict__ kb)
{
    const size_t total = (size_t)NPOOL * DIM / 4;   // 8,388,608 float4
    size_t stride = (size_t)gridDim.x * blockDim.x;
    for (size_t i = blockIdx.x * (size_t)blockDim.x + threadIdx.x; i < total; i += stride) {
        float4 v = k4[i];
        us4 o;
        o.x = f2bf(v.x); o.y = f2bf(v.y); o.z = f2bf(v.z); o.w = f2bf(v.w);
        kb[i] = o;
    }
}

// ---------------------------------------------------------------------------
// P2: per-row ||q||, tau, q->bf16, zero cnt; tail blocks transpose w_out.
// grid = NQ + PD, block = 128
// ---------------------------------------------------------------------------
__global__ __launch_bounds__(128)
void prep_q(const float* __restrict__ q, unsigned short* __restrict__ qb16,
            float* __restrict__ tau, int* __restrict__ cnt,
            const float* __restrict__ w, float* __restrict__ wt)
{
    const int bid = blockIdx.x, t = threadIdx.x;
    if (bid >= NQ) {                       // transpose w_out [o][d] -> wt [d][o]
        int o = bid - NQ;
        wt[t * PD + o]         = w[o * PD + t];
        wt[(t + 128) * PD + o] = w[o * PD + t + 128];
        return;
    }
    const int row = bid;
    float v = q[(size_t)row * DIM + t];
    qb16[(size_t)row * DIM + t] = f2bf(v);
    float s = v * v;
    #pragma unroll
    for (int off = 32; off; off >>= 1) s += __shfl_xor(s, off);
    __shared__ float part[2];
    if ((t & 63) == 0) part[t >> 6] = s;
    __syncthreads();
    if (t == 0) {
        float nn = part[0] + part[1];
        tau[row] = ZTHR * 0.02f * sqrtf(nn);
        cnt[row] = 0;
    }
}

// ---------------------------------------------------------------------------
// A: bf16 MFMA scores. Wave-PRIVATE double-buffered LDS staged via
//    global_load_lds DMA; counted vmcnt(4) pipelining; ZERO barriers in the
//    main loop (each wave stages and reads only its own 4 KB region).
//    Per-lane max/branch filter -> LDS candidate buffer, bulk flush at end.
// grid = 32 qblocks * 64 slabs = 2048 blocks, 256 threads (4 waves)
// ---------------------------------------------------------------------------
__global__ __launch_bounds__(256, 4)
void score_filter_kernel(const unsigned short* __restrict__ qb16, // [NQ][DIM]
                         const unsigned short* __restrict__ kb16, // [NPOOL][DIM]
                         const float* __restrict__ tau,
                         int* __restrict__ cnt,
                         int* __restrict__ cand_i)                // [NQ][CAP]
{
    __shared__ char ksh[2][4][4096];       // [buf][wave][16 rows x 256 B]
    __shared__ float taus[QBA];
    __shared__ unsigned int lbuf[LBUF];
    __shared__ int lcnt;

    // XCD-chunked swizzle (2048 blocks, 8 XCDs): slab varies slowly per XCD
    const int bid  = blockIdx.x;
    const int swz  = (bid & 7) * 256 + (bid >> 3);
    const int slab = swz >> 5;       // 0..63
    const int qblk = swz & 31;       // 0..31
    const int qbase = qblk * QBA;
    const int kslab = slab * SLABK;

    const int t    = threadIdx.x;
    const int lane = t & 63;
    const int wave = t >> 6;
    const int lrow = lane >> 4;      // 0..3
    const int lcol = lane & 15;      // 0..15
    const int srcb = lcol * 16;

    // Stage chunk CH's 16 wave-own keys into ksh[B][wave]:
    // LDS linear (row r at r*256), source 16B-unit XOR-swizzled by (r&7)<<4.
#define STAGE(CH, B) do {                                                      \
        const char* kb_ = (const char*)kb16                                    \
            + (size_t)(kslab + (CH) * CKA + wave * 16) * 256;                  \
        _Pragma("unroll")                                                      \
        for (int j_ = 0; j_ < 4; ++j_) {                                       \
            int r_ = j_ * 4 + lrow;                                            \
            gload_lds16(kb_ + (size_t)r_ * 256 + (srcb ^ ((r_ & 7) << 4)),     \
                        &ksh[B][wave][j_ * 1024]);                             \
        } } while (0)

#define WAITVM(N) do {                                                         \
        asm volatile("s_waitcnt vmcnt(" #N ")" ::: "memory");                  \
        __builtin_amdgcn_sched_barrier(0); } while (0)

    if (t == 0) lcnt = 0;
    if (t < QBA) taus[t] = tau[qbase + t];
    STAGE(0, 0);

    // Q fragments: A[row=lcol][k=lrow*8+j], rowgroup g, kchunk kc
    bf16x8 qf[4][4];
    #pragma unroll
    for (int g = 0; g < 4; ++g)
        #pragma unroll
        for (int kc = 0; kc < 4; ++kc)
            qf[g][kc] = *(const bf16x8*)&qb16[(size_t)(qbase + g * 16 + lcol) * DIM
                                             + kc * 32 + lrow * 8];

    __syncthreads();   // taus visible (one-time full drain, STAGE(0) lands)

    float tmin = 1e30f;
    #pragma unroll
    for (int g = 0; g < 4; ++g)
        #pragma unroll
        for (int r = 0; r < 4; ++r)
            tmin = fminf(tmin, taus[g * 16 + lrow * 4 + r]);

    // chunk-invariant swizzled read offsets (this lane reads local key row lcol)
    int roff[4];
    #pragma unroll
    for (int kc = 0; kc < 4; ++kc)
        roff[kc] = lcol * 256 + ((kc * 64 + lrow * 16) ^ ((lcol & 7) << 4));

#define COMPUTE(B, CH) do {                                                     \
        const char* bp_ = &ksh[B][wave][0];                                     \
        f32x4 acc[4] = {{0,0,0,0},{0,0,0,0},{0,0,0,0},{0,0,0,0}};               \
        _Pragma("unroll")                                                       \
        for (int kc = 0; kc < 4; ++kc) {                                        \
            bf16x8 bf = *(const bf16x8*)(bp_ + roff[kc]);                       \
            _Pragma("unroll")                                                   \
            for (int g = 0; g < 4; ++g)                                         \
                acc[g] = __builtin_amdgcn_mfma_f32_16x16x32_bf16(               \
                             qf[g][kc], bf, acc[g], 0, 0, 0);                   \
        }                                                                       \
        float mx0 = fmaxf(fmaxf(acc[0][0], acc[0][1]), fmaxf(acc[0][2], acc[0][3])); \
        float mx1 = fmaxf(fmaxf(acc[1][0], acc[1][1]), fmaxf(acc[1][2], acc[1][3])); \
        float mx2 = fmaxf(fmaxf(acc[2][0], acc[2][1]), fmaxf(acc[2][2], acc[2][3])); \
        float mx3 = fmaxf(fmaxf(acc[3][0], acc[3][1]), fmaxf(acc[3][2], acc[3][3])); \
        float mx  = fmaxf(fmaxf(mx0, mx1), fmaxf(mx2, mx3));                    \
        if (mx > tmin) {                                                        \
            const unsigned keyl = (unsigned)((CH) * CKA + wave * 16 + lcol);    \
            _Pragma("unroll")                                                   \
            for (int g = 0; g < 4; ++g) {                                       \
                _Pragma("unroll")                                               \
                for (int r = 0; r < 4; ++r) {                                   \
                    if (acc[g][r] > taus[g * 16 + lrow * 4 + r]) {              \
                        int idx = atomicAdd(&lcnt, 1);                          \
                        if (idx < LBUF)                                         \
                            lbuf[idx] = ((unsigned)(g * 16 + lrow * 4 + r) << 12) | keyl; \
                    }                                                           \
                }                                                               \
            }                                                                   \
        } } while (0)

    // Main loop: stage ch+1, wait only for ch (vmcnt(4) = the 4 just-issued
    // loads may remain in flight), compute ch. No barriers — wave-private.
    #pragma unroll 1
    for (int ch = 0; ch < NCH - 2; ch += 2) {
        STAGE(ch + 1, 1);
        WAITVM(4);
        COMPUTE(0, ch);
        STAGE(ch + 2, 0);
        WAITVM(4);
        COMPUTE(1, ch + 1);
    }
    STAGE(NCH - 1, 1);
    WAITVM(4);
    COMPUTE(0, NCH - 2);
    WAITVM(0);
    COMPUTE(1, NCH - 1);
#undef STAGE
#undef WAITVM
#undef COMPUTE

    __syncthreads();   // lbuf/lcnt visible
    const int n = min(lcnt, LBUF);
    for (int i = t; i < n; i += 256) {
        unsigned e = lbuf[i];
        int row  = qbase + (int)(e >> 12);
        int keyg = kslab + (int)(e & 4095u);
        int slot = atomicAdd(&cnt[row], 1);
        if (slot < CAP) cand_i[(size_t)row * CAP + slot] = keyg;
    }
}

// ---------------------------------------------------------------------------
// B: f32 rescore of candidates -> exact top-32 -> softmax -> gather -> matmul
// grid = NQ, 256 threads
// ---------------------------------------------------------------------------
__global__ __launch_bounds__(256)
void rescore_agg_kernel(const float* __restrict__ q,
                        const float* __restrict__ keys,
                        const float* __restrict__ pool,
                        const float* __restrict__ wt,
                        const int* __restrict__ cnt,
                        const int* __restrict__ cand_i,
                        float* __restrict__ out)
{
    __shared__ float qrow[DIM];
    __shared__ float ls[CAP];
    __shared__ int   li[CAP];
    __shared__ float red_s[4];
    __shared__ int   red_p[4];
    __shared__ float sel_s[TOPK];
    __shared__ int   sel_i[TOPK];
    __shared__ float wts[TOPK];
    __shared__ float agg[PD];

    const int t   = threadIdx.x;
    const int row = blockIdx.x;
    const int n   = min(cnt[row], CAP);

    if (t < DIM) qrow[t] = q[(size_t)row * DIM + t];
    for (int i = t; i < CAP; i += 256) { ls[i] = -1e30f; li[i] = 0; }
    __syncthreads();

    // rescore: 16 groups of 16 lanes; group handles candidates strided by 16
    const int grp = t >> 4, gl = t & 15;
    for (int c = grp; c < n; c += 16) {
        int ki = cand_i[(size_t)row * CAP + c];
        const float4* kr4 = (const float4*)(keys + (size_t)ki * DIM + gl * 8);
        float4 k0 = kr4[0], k1 = kr4[1];
        const float* qq = &qrow[gl * 8];
        float s = qq[0]*k0.x + qq[1]*k0.y + qq[2]*k0.z + qq[3]*k0.w
                + qq[4]*k1.x + qq[5]*k1.y + qq[6]*k1.z + qq[7]*k1.w;
        s += __shfl_xor(s, 1); s += __shfl_xor(s, 2);
        s += __shfl_xor(s, 4); s += __shfl_xor(s, 8);
        if (gl == 0) { ls[c] = s; li[c] = ki; }
    }
    __syncthreads();

    // exact top-32 (iterative argmax over CAP slots; tie-break lower key idx)
    for (int k = 0; k < TOPK; ++k) {
        float bs = ls[t]; int bp = t;
        {
            float s2 = ls[t + 256];
            if (s2 > bs || (s2 == bs && li[t + 256] < li[bp])) { bs = s2; bp = t + 256; }
        }
        #pragma unroll
        for (int off = 1; off < 64; off <<= 1) {
            float os = __shfl_xor(bs, off);
            int   op = __shfl_xor(bp, off);
            if (os > bs || (os == bs && li[op] < li[bp])) { bs = os; bp = op; }
        }
        if ((t & 63) == 0) { red_s[t >> 6] = bs; red_p[t >> 6] = bp; }
        __syncthreads();
        if (t == 0) {
            float best = red_s[0]; int p = red_p[0];
            #pragma unroll
            for (int w = 1; w < 4; ++w) {
                float s2 = red_s[w]; int p2 = red_p[w];
                if (s2 > best || (s2 == best && li[p2] < li[p])) { best = s2; p = p2; }
            }
            sel_s[k] = best; sel_i[k] = li[p];
            ls[p] = -1e30f;
        }
        __syncthreads();
    }

    // softmax over 32 (sel_s[0] is max; empty slots give exp(-huge)=0)
    if (t < 64) {
        float e = (t < TOPK) ? expf(sel_s[t] - sel_s[0]) : 0.f;
        float v = e;
        #pragma unroll
        for (int off = 1; off < 64; off <<= 1) v += __shfl_xor(v, off);
        if (t < TOPK) wts[t] = e / v;
    }
    __syncthreads();

    // weighted gather: thread t owns pool dim t
    float a = 0.f;
    #pragma unroll
    for (int k = 0; k < TOPK; ++k)
        a += wts[k] * pool[(size_t)sel_i[k] * PD + t];
    agg[t] = a;
    __syncthreads();

    // out[row][o] = sum_d agg[d] * wt[d][o]
    float o = 0.f;
    #pragma unroll 8
    for (int d = 0; d < PD; ++d)
        o += agg[d] * wt[d * PD + t];
    out[(size_t)row * PD + t] = o;
}

extern "C" void kernel_launch(void* const* d_in, const int* in_sizes, int n_in,
                              void* d_out, int out_size, void* d_ws, size_t ws_size,
                              hipStream_t stream)
{
    const float* q    = (const float*)d_in[0];   // [2,1024,128]
    const float* pool = (const float*)d_in[1];   // [262144,256]
    const float* keys = (const float*)d_in[2];   // [262144,128]
    const float* w    = (const float*)d_in[3];   // [256,256]
    float* out = (float*)d_out;

    char* ws = (char*)d_ws;
    unsigned short* kb16  = (unsigned short*)(ws);                    // 67,108,864 B
    unsigned short* qb16  = (unsigned short*)(ws + 67108864);         //    524,288 B
    float*          tau   = (float*)(ws + 67633152);                  //      8,192 B
    int*            cnt   = (int*)(ws + 67641344);                    //      8,192 B
    int*            candi = (int*)(ws + 67649536);                    //  4,194,304 B
    float*          wt    = (float*)(ws + 71843840);                  //    262,144 B

    hipLaunchKernelGGL(convert_keys, dim3(2048), dim3(256), 0, stream,
                       (const float4*)keys, (us4*)kb16);
    hipLaunchKernelGGL(prep_q, dim3(NQ + PD), dim3(128), 0, stream,
                       q, qb16, tau, cnt, w, wt);
    hipLaunchKernelGGL(score_filter_kernel, dim3(2048), dim3(256), 0, stream,
                       qb16, kb16, tau, cnt, candi);
    hipLaunchKernelGGL(rescore_agg_kernel, dim3(NQ), dim3(256), 0, stream,
                       q, keys, pool, wt, cnt, candi, out);
}